// Round 12
// baseline (355.991 us; speedup 1.0000x reference)
//
#include <hip/hip_runtime.h>

#define N_NODES 100000
#define N_EDGES 1600000
#define INC 128
#define HIDC 128
#define OUTC 64

// Binned scatter geometry: bucket = target >> 9 (512 targets/bucket)
constexpr int BSH = 9;
constexpr int BTGT = 1 << BSH;                                // 512
constexpr int NBUCK = (N_NODES + BTGT - 1) / BTGT;            // 196
constexpr int BCAP = 10240;                                   // fixed bucket capacity (mean 8163, sd~90)
constexpr int BIN_TILE = 2048;
constexpr int BIN_EPT = BIN_TILE / 256;                       // 8
constexpr int NBINBLK = (N_EDGES + BIN_TILE - 1) / BIN_TILE;  // 782

// ---------------- bf16 helpers ----------------

__device__ __forceinline__ float blo(unsigned u) { return __uint_as_float(u << 16); }
__device__ __forceinline__ float bhi(unsigned u) { return __uint_as_float(u & 0xFFFF0000u); }
__device__ __forceinline__ unsigned pack_bf2(float a, float b) {
    unsigned ua = __float_as_uint(a);
    ua = (ua + 0x7FFFu + ((ua >> 16) & 1u)) >> 16;
    unsigned ub = __float_as_uint(b);
    ub = (ub + 0x7FFFu + ((ub >> 16) & 1u)) >> 16;
    return ua | (ub << 16);
}

// ---------------- fixed-capacity binned CSR build (no pre-count) ----------------

__global__ void k_binit(int* __restrict__ bcur) {
    int b = threadIdx.x;
    if (b < NBUCK) bcur[b] = b * BCAP;
}

// Pass A: tile 2048 edges -> LDS histogram over buckets -> reserve per-bucket
// chunks (1 global atomic per block,bucket) -> write packed (src<<9)|localT
// into fixed-capacity bucket regions in ~10-edge chunks (line-friendly).
__global__ __launch_bounds__(256) void k_bin(const int* __restrict__ ei,
                                             int* __restrict__ bcur,
                                             unsigned* __restrict__ staging) {
    __shared__ int cnt[256];
    __shared__ int base[256];
    const int tid = threadIdx.x;
    cnt[tid] = 0;
    __syncthreads();
    const int e0 = blockIdx.x * BIN_TILE;
    unsigned pk[BIN_EPT];
    int bk[BIN_EPT];
#pragma unroll
    for (int r = 0; r < BIN_EPT; ++r) {
        int e = e0 + r * 256 + tid;
        if (e < N_EDGES) {
            int t = __builtin_nontemporal_load(ei + N_EDGES + e);
            int s = __builtin_nontemporal_load(ei + e);
            bk[r] = t >> BSH;
            pk[r] = ((unsigned)s << BSH) | (unsigned)(t & (BTGT - 1));
            atomicAdd(&cnt[bk[r]], 1);
        } else {
            bk[r] = -1;
        }
    }
    __syncthreads();
    if (tid < NBUCK) {
        int c = cnt[tid];
        base[tid] = (c > 0) ? atomicAdd(&bcur[tid], c) : 0;
    }
    __syncthreads();
#pragma unroll
    for (int r = 0; r < BIN_EPT; ++r) {
        if (bk[r] >= 0) {
            int g = atomicAdd(&base[bk[r]], 1);
            staging[g] = pk[r];
        }
    }
}

// One block: scan the 196 bucket totals -> bucket CSR bases; offs[N] = E.
__global__ void k_bucket_scan(const int* __restrict__ bcur, int* __restrict__ bbase,
                              int* __restrict__ offs) {
    __shared__ int sdata[256];
    const int tid = threadIdx.x;
    int v = (tid < NBUCK) ? (bcur[tid] - tid * BCAP) : 0;
    sdata[tid] = v;
    __syncthreads();
    for (int off = 1; off < 256; off <<= 1) {
        int t = (tid >= off) ? sdata[tid - off] : 0;
        __syncthreads();
        sdata[tid] += t;
        __syncthreads();
    }
    if (tid < NBUCK) bbase[tid] = sdata[tid] - v;
    if (tid == 0) offs[N_NODES] = N_EDGES;
}

// Pass B: one block per bucket. Count per-target in LDS, 512-wide LDS scan ->
// offs + dinv + cursors, then place csr_row within the bucket's contiguous
// ~32KB window (full lines, no global atomics).
__global__ __launch_bounds__(256) void k_scatter2(const unsigned* __restrict__ staging,
                                                  const int* __restrict__ bcur,
                                                  const int* __restrict__ bbase,
                                                  int* __restrict__ offs,
                                                  float* __restrict__ dinv,
                                                  int* __restrict__ csr_row) {
    __shared__ int cnt[BTGT];
    __shared__ int pos[BTGT];
    __shared__ int sdata[256];
    const int b = blockIdx.x;
    const int tid = threadIdx.x;
    const int segb = b * BCAP;
    const int n = bcur[b] - segb;
    const int g0 = b << BSH;
    const int bb = bbase[b];
    cnt[tid] = 0;
    cnt[tid + 256] = 0;
    __syncthreads();
    for (int j = tid; j < n; j += 256) {
        atomicAdd(&cnt[staging[segb + j] & (BTGT - 1)], 1);
    }
    __syncthreads();
    const int c0 = cnt[2 * tid], c1 = cnt[2 * tid + 1];
    const int s = c0 + c1;
    sdata[tid] = s;
    __syncthreads();
    for (int off = 1; off < 256; off <<= 1) {
        int t = (tid >= off) ? sdata[tid - off] : 0;
        __syncthreads();
        sdata[tid] += t;
        __syncthreads();
    }
    const int texcl = sdata[tid] - s;
    const int o0 = bb + texcl;
    const int o1 = o0 + c0;
    const int gg0 = g0 + 2 * tid, gg1 = g0 + 2 * tid + 1;
    if (gg0 < N_NODES) {
        offs[gg0] = o0;
        dinv[gg0] = (c0 > 0) ? rsqrtf((float)c0) : 0.f;
    }
    if (gg1 < N_NODES) {
        offs[gg1] = o1;
        dinv[gg1] = (c1 > 0) ? rsqrtf((float)c1) : 0.f;
    }
    pos[2 * tid] = o0;
    pos[2 * tid + 1] = o1;
    __syncthreads();
    for (int j = tid; j < n; j += 256) {
        unsigned p = staging[segb + j];
        int lt = p & (BTGT - 1);
        int src = (int)(p >> BSH);
        int pp = atomicAdd(&pos[lt], 1);
        csr_row[pp] = src;
    }
}

// ---------------- dinv-scaled GEMM -> bf16, conflict-free 4x8 tile ----------------

template <int BN, int OUTTOT>
__global__ __launch_bounds__(256) void k_gemm3(const float* __restrict__ X,
                                               const float* __restrict__ W,
                                               const float* __restrict__ dinv,
                                               unsigned short* __restrict__ outb) {
    constexpr int OG = OUTTOT / 8;   // out groups: 16 (L1) / 8 (L2)
    constexpr int NG = 256 / OG;     // node groups: 16 / 32; NG*4 == BN
    static_assert(NG * 4 == BN, "tile mismatch");
    constexpr int KC = 32;           // k-chunk
    constexpr int HW = OUTTOT / 2;   // half-width floats (64 / 32)
    constexpr int XITER = (BN * KC) / 1024;     // 2 / 4
    constexpr int WITER = (KC * OUTTOT) / 1024; // 4 / 2

    __shared__ float xs[BN][KC + 4];
    __shared__ float wa[KC][HW];
    __shared__ float wb[KC][HW];

    const int tid = threadIdx.x;
    const int oq = tid % OG;
    const int nq = tid / OG;
    const int n0 = blockIdx.x * BN;
    float acc[4][8] = {};

    for (int kc = 0; kc < 128; kc += KC) {
#pragma unroll
        for (int m = 0; m < XITER; ++m) {
            int q = tid + 256 * m;
            int row = q / (KC / 4);
            int kq = q % (KC / 4);
            int nn = n0 + row;
            float4 v = make_float4(0.f, 0.f, 0.f, 0.f);
            if (nn < N_NODES)
                v = *reinterpret_cast<const float4*>(X + (size_t)nn * 128 + kc + kq * 4);
            *reinterpret_cast<float4*>(&xs[row][kq * 4]) = v;
        }
#pragma unroll
        for (int m = 0; m < WITER; ++m) {
            int q = tid + 256 * m;
            int row = q / (OUTTOT / 4);
            int fq = q % (OUTTOT / 4);
            float4 v = *reinterpret_cast<const float4*>(W + (size_t)(kc + row) * OUTTOT + fq * 4);
            float* dst = (fq & 1) ? &wb[row][(fq >> 1) * 4] : &wa[row][(fq >> 1) * 4];
            *reinterpret_cast<float4*>(dst) = v;
        }
        __syncthreads();
#pragma unroll 8
        for (int k = 0; k < KC; ++k) {
            const float4 w0 = *reinterpret_cast<const float4*>(&wa[k][oq * 4]);
            const float4 w1 = *reinterpret_cast<const float4*>(&wb[k][oq * 4]);
#pragma unroll
            for (int j = 0; j < 4; ++j) {
                float xv = xs[nq + NG * j][k];
                acc[j][0] += xv * w0.x;
                acc[j][1] += xv * w0.y;
                acc[j][2] += xv * w0.z;
                acc[j][3] += xv * w0.w;
                acc[j][4] += xv * w1.x;
                acc[j][5] += xv * w1.y;
                acc[j][6] += xv * w1.z;
                acc[j][7] += xv * w1.w;
            }
        }
        __syncthreads();
    }
#pragma unroll
    for (int j = 0; j < 4; ++j) {
        int nn = n0 + nq + NG * j;
        if (nn < N_NODES) {
            float s = dinv[nn];
            uint4 pkv;
            pkv.x = pack_bf2(acc[j][0] * s, acc[j][1] * s);
            pkv.y = pack_bf2(acc[j][2] * s, acc[j][3] * s);
            pkv.z = pack_bf2(acc[j][4] * s, acc[j][5] * s);
            pkv.w = pack_bf2(acc[j][6] * s, acc[j][7] * s);
            *reinterpret_cast<uint4*>(outb + (size_t)nn * OUTTOT + oq * 8) = pkv;
        }
    }
}

// ---------------- layer-1 aggregation: XCD feature-half split + deep ILP ----------------
// 8 units = (4 node-ranges x 2 feature-halves) via blockIdx&7 -> each XCD
// fills only 12.8MB of half-rows (1x128B line per edge, vs 2 lines full-row).
// Per wave: 4 ADJACENT nodes x U=2 chains = 8 gathers in flight per lane.
// LPR=8 lanes cover the 128B half-row with uint4; shfl_xor cross-slot reduce.

template <bool RELU>
__global__ __launch_bounds__(256) void k_aggs(const uint4* __restrict__ hs,
                                              const int* __restrict__ csr_row,
                                              const int* __restrict__ offs,
                                              const float* __restrict__ dinv,
                                              const float* __restrict__ bias,
                                              float* __restrict__ out) {
    constexpr int LPR = 8;           // lanes per half-row (8 x 16B = 128B)
    constexpr int SLOTS = 8;         // edge slots per wave
    constexpr int U = 2;             // chain depth per node
    constexpr int NPW = 4;           // nodes per wave
    constexpr int RQ = 16;           // uint4 per full 128-feature row
    constexpr int NRANGES = 4;
    constexpr int RLEN = N_NODES / NRANGES;  // 25000 (div by 4)

    const int pass = blockIdx.x & 7;
    const int grp = pass & 1;
    const int rng = pass >> 1;
    const int lo = rng * RLEN;
    const int hi = lo + RLEN;
    const int lane = threadIdx.x & 63;
    const int sub = lane >> 3;       // 0..7 edge slot
    const int q = lane & 7;          // uint4 index within half-row
    const int lwid = (blockIdx.x >> 3) * 4 + (threadIdx.x >> 6);
    const int nlw = (gridDim.x >> 3) * 4;

    for (int t0 = lo + lwid * NPW; t0 < hi; t0 += nlw * NPW) {
        int ss[NPW], ee[NPW], jj[NPW];
#pragma unroll
        for (int i = 0; i < NPW; ++i) {
            ss[i] = offs[t0 + i];
            ee[i] = offs[t0 + i + 1];
            jj[i] = ss[i];
        }
        float a0[8] = {}, a1[8] = {}, a2[8] = {}, a3[8] = {};
        bool more = true;
        while (more) {
            int r[NPW][U];
#pragma unroll
            for (int i = 0; i < NPW; ++i)
#pragma unroll
                for (int u = 0; u < U; ++u) {
                    int p = jj[i] + u * SLOTS + sub;
                    r[i][u] = (p < ee[i]) ? __builtin_nontemporal_load(csr_row + p) : -1;
                }
            uint4 v[NPW][U];
#pragma unroll
            for (int i = 0; i < NPW; ++i)
#pragma unroll
                for (int u = 0; u < U; ++u) {
                    v[i][u] = make_uint4(0u, 0u, 0u, 0u);
                    if (r[i][u] >= 0) v[i][u] = hs[(size_t)r[i][u] * RQ + grp * LPR + q];
                }
#pragma unroll
            for (int u = 0; u < U; ++u) {
                a0[0] += blo(v[0][u].x); a0[1] += bhi(v[0][u].x);
                a0[2] += blo(v[0][u].y); a0[3] += bhi(v[0][u].y);
                a0[4] += blo(v[0][u].z); a0[5] += bhi(v[0][u].z);
                a0[6] += blo(v[0][u].w); a0[7] += bhi(v[0][u].w);
                a1[0] += blo(v[1][u].x); a1[1] += bhi(v[1][u].x);
                a1[2] += blo(v[1][u].y); a1[3] += bhi(v[1][u].y);
                a1[4] += blo(v[1][u].z); a1[5] += bhi(v[1][u].z);
                a1[6] += blo(v[1][u].w); a1[7] += bhi(v[1][u].w);
                a2[0] += blo(v[2][u].x); a2[1] += bhi(v[2][u].x);
                a2[2] += blo(v[2][u].y); a2[3] += bhi(v[2][u].y);
                a2[4] += blo(v[2][u].z); a2[5] += bhi(v[2][u].z);
                a2[6] += blo(v[2][u].w); a2[7] += bhi(v[2][u].w);
                a3[0] += blo(v[3][u].x); a3[1] += bhi(v[3][u].x);
                a3[2] += blo(v[3][u].y); a3[3] += bhi(v[3][u].y);
                a3[4] += blo(v[3][u].z); a3[5] += bhi(v[3][u].z);
                a3[6] += blo(v[3][u].w); a3[7] += bhi(v[3][u].w);
            }
            more = false;
#pragma unroll
            for (int i = 0; i < NPW; ++i) {
                jj[i] += U * SLOTS;
                more = more || (jj[i] < ee[i]);
            }
        }
#pragma unroll
        for (int off = 32; off >= LPR; off >>= 1) {
#pragma unroll
            for (int i = 0; i < 8; ++i) {
                a0[i] += __shfl_xor(a0[i], off);
                a1[i] += __shfl_xor(a1[i], off);
                a2[i] += __shfl_xor(a2[i], off);
                a3[i] += __shfl_xor(a3[i], off);
            }
        }
        if (lane < LPR) {
            const float* bp = bias + grp * 64 + q * 8;
            const float4 b0 = *reinterpret_cast<const float4*>(bp);
            const float4 b1 = *reinterpret_cast<const float4*>(bp + 4);
            float* ap[NPW] = {a0, a1, a2, a3};
#pragma unroll
            for (int i = 0; i < NPW; ++i) {
                const float dt = dinv[t0 + i];
                float* a = ap[i];
                float4 r0, r1;
                r0.x = a[0] * dt + b0.x; r0.y = a[1] * dt + b0.y;
                r0.z = a[2] * dt + b0.z; r0.w = a[3] * dt + b0.w;
                r1.x = a[4] * dt + b1.x; r1.y = a[5] * dt + b1.y;
                r1.z = a[6] * dt + b1.z; r1.w = a[7] * dt + b1.w;
                if (RELU) {
                    r0.x = fmaxf(r0.x, 0.f); r0.y = fmaxf(r0.y, 0.f);
                    r0.z = fmaxf(r0.z, 0.f); r0.w = fmaxf(r0.w, 0.f);
                    r1.x = fmaxf(r1.x, 0.f); r1.y = fmaxf(r1.y, 0.f);
                    r1.z = fmaxf(r1.z, 0.f); r1.w = fmaxf(r1.w, 0.f);
                }
                float* po = out + (size_t)(t0 + i) * HIDC + grp * 64 + q * 8;
                *reinterpret_cast<float4*>(po) = r0;
                *reinterpret_cast<float4*>(po + 4) = r1;
            }
        }
    }
}

// ---------------- layer-2 aggregation (control, unchanged from R10) ----------------

template <int OC, int U, bool RELU>
__global__ __launch_bounds__(256) void k_aggp(const uint4* __restrict__ hs,
                                              const int* __restrict__ csr_row,
                                              const int* __restrict__ offs,
                                              const float* __restrict__ dinv,
                                              const float* __restrict__ bias,
                                              float* __restrict__ out) {
    constexpr int LPR = (OC * 2) / 16;   // 8 for OC=64
    constexpr int SLOTS = 64 / LPR;      // 8
    const int lane = threadIdx.x & 63;
    const int sub = lane / LPR;
    const int q = lane % LPR;
    const int wid = (blockIdx.x * 4) + (threadIdx.x >> 6);
    const int nwaves = gridDim.x * 4;

    for (int t0 = wid * 2; t0 < N_NODES; t0 += nwaves * 2) {
        const int t1 = t0 + 1;
        const int s0 = offs[t0], e0 = offs[t0 + 1];
        const int s1 = offs[t1], e1 = offs[t1 + 1];
        float a0[8] = {}, a1[8] = {};
        int j0 = s0, j1 = s1;
        while (j0 < e0 || j1 < e1) {
            int r0[U], r1[U];
#pragma unroll
            for (int u = 0; u < U; ++u) {
                int jj = j0 + u * SLOTS + sub;
                r0[u] = (jj < e0) ? __builtin_nontemporal_load(csr_row + jj) : -1;
            }
#pragma unroll
            for (int u = 0; u < U; ++u) {
                int jj = j1 + u * SLOTS + sub;
                r1[u] = (jj < e1) ? __builtin_nontemporal_load(csr_row + jj) : -1;
            }
            uint4 v0[U], v1[U];
#pragma unroll
            for (int u = 0; u < U; ++u) {
                v0[u] = make_uint4(0u, 0u, 0u, 0u);
                if (r0[u] >= 0) v0[u] = hs[(size_t)r0[u] * LPR + q];
            }
#pragma unroll
            for (int u = 0; u < U; ++u) {
                v1[u] = make_uint4(0u, 0u, 0u, 0u);
                if (r1[u] >= 0) v1[u] = hs[(size_t)r1[u] * LPR + q];
            }
#pragma unroll
            for (int u = 0; u < U; ++u) {
                a0[0] += blo(v0[u].x); a0[1] += bhi(v0[u].x);
                a0[2] += blo(v0[u].y); a0[3] += bhi(v0[u].y);
                a0[4] += blo(v0[u].z); a0[5] += bhi(v0[u].z);
                a0[6] += blo(v0[u].w); a0[7] += bhi(v0[u].w);
                a1[0] += blo(v1[u].x); a1[1] += bhi(v1[u].x);
                a1[2] += blo(v1[u].y); a1[3] += bhi(v1[u].y);
                a1[4] += blo(v1[u].z); a1[5] += bhi(v1[u].z);
                a1[6] += blo(v1[u].w); a1[7] += bhi(v1[u].w);
            }
            j0 += U * SLOTS;
            j1 += U * SLOTS;
        }
#pragma unroll
        for (int off = 32; off >= LPR; off >>= 1) {
#pragma unroll
            for (int i = 0; i < 8; ++i) {
                a0[i] += __shfl_xor(a0[i], off);
                a1[i] += __shfl_xor(a1[i], off);
            }
        }
        if (lane < LPR) {
            const float4 b0 = *reinterpret_cast<const float4*>(bias + lane * 8);
            const float4 b1 = *reinterpret_cast<const float4*>(bias + lane * 8 + 4);
            const float d0 = dinv[t0], d1 = dinv[t1];
            float4 r0, r1, r2, r3;
            r0.x = a0[0] * d0 + b0.x; r0.y = a0[1] * d0 + b0.y;
            r0.z = a0[2] * d0 + b0.z; r0.w = a0[3] * d0 + b0.w;
            r1.x = a0[4] * d0 + b1.x; r1.y = a0[5] * d0 + b1.y;
            r1.z = a0[6] * d0 + b1.z; r1.w = a0[7] * d0 + b1.w;
            r2.x = a1[0] * d1 + b0.x; r2.y = a1[1] * d1 + b0.y;
            r2.z = a1[2] * d1 + b0.z; r2.w = a1[3] * d1 + b0.w;
            r3.x = a1[4] * d1 + b1.x; r3.y = a1[5] * d1 + b1.y;
            r3.z = a1[6] * d1 + b1.z; r3.w = a1[7] * d1 + b1.w;
            if (RELU) {
                r0.x = fmaxf(r0.x, 0.f); r0.y = fmaxf(r0.y, 0.f);
                r0.z = fmaxf(r0.z, 0.f); r0.w = fmaxf(r0.w, 0.f);
                r1.x = fmaxf(r1.x, 0.f); r1.y = fmaxf(r1.y, 0.f);
                r1.z = fmaxf(r1.z, 0.f); r1.w = fmaxf(r1.w, 0.f);
                r2.x = fmaxf(r2.x, 0.f); r2.y = fmaxf(r2.y, 0.f);
                r2.z = fmaxf(r2.z, 0.f); r2.w = fmaxf(r2.w, 0.f);
                r3.x = fmaxf(r3.x, 0.f); r3.y = fmaxf(r3.y, 0.f);
                r3.w = fmaxf(r3.w, 0.f); r3.z = fmaxf(r3.z, 0.f);
            }
            float* p0 = out + (size_t)t0 * OC + lane * 8;
            float* p1 = out + (size_t)t1 * OC + lane * 8;
            *reinterpret_cast<float4*>(p0) = r0;
            *reinterpret_cast<float4*>(p0 + 4) = r1;
            *reinterpret_cast<float4*>(p1) = r2;
            *reinterpret_cast<float4*>(p1 + 4) = r3;
        }
    }
}

// ---------------- launch ----------------

extern "C" void kernel_launch(void* const* d_in, const int* in_sizes, int n_in,
                              void* d_out, int out_size, void* d_ws, size_t ws_size,
                              hipStream_t stream) {
    const float* x  = (const float*)d_in[0];
    const int*   ei = (const int*)d_in[1];
    const float* W1 = (const float*)d_in[2];
    const float* b1 = (const float*)d_in[3];
    const float* W2 = (const float*)d_in[4];
    const float* b2 = (const float*)d_in[5];
    float* out = (float*)d_out;

    char* w = (char*)d_ws;
    auto alloc = [&](size_t bytes) {
        void* p = (void*)w;
        w += (bytes + 255) & ~(size_t)255;
        return p;
    };
    float* dinv    = (float*)alloc((size_t)N_NODES * 4);
    int*   offs    = (int*)alloc((size_t)(N_NODES + 1) * 4);
    int*   bcur    = (int*)alloc((size_t)NBUCK * 4);
    int*   bbase   = (int*)alloc(256 * 4);
    unsigned* staging = (unsigned*)alloc((size_t)NBUCK * BCAP * 4); // 8.0 MB
    int*   csr_row = (int*)alloc((size_t)N_EDGES * 4);
    unsigned short* hs1 = (unsigned short*)alloc((size_t)N_NODES * HIDC * 2); // bf16
    float* h       = (float*)alloc((size_t)N_NODES * HIDC * 4);
    unsigned short* hs2 = hs1; // bf16, reuse (hs1 dead after layer-1 agg)

    // CSR + norm build (fixed-capacity buckets; no pre-count)
    k_binit<<<1, 256, 0, stream>>>(bcur);
    k_bin<<<NBINBLK, 256, 0, stream>>>(ei, bcur, staging);
    k_bucket_scan<<<1, 256, 0, stream>>>(bcur, bbase, offs);
    k_scatter2<<<NBUCK, 256, 0, stream>>>(staging, bcur, bbase, offs, dinv, csr_row);

    // layer 1: 64 nodes x 128 outs per block
    k_gemm3<64, HIDC><<<(N_NODES + 63) / 64, 256, 0, stream>>>(x, W1, dinv, hs1);
    k_aggs<true><<<2048, 256, 0, stream>>>((const uint4*)hs1, csr_row, offs, dinv, b1, h);

    // layer 2: 128 nodes x 64 outs per block
    k_gemm3<128, OUTC><<<(N_NODES + 127) / 128, 256, 0, stream>>>(h, W2, dinv, hs2);
    k_aggp<OUTC, 2, false><<<2048, 256, 0, stream>>>((const uint4*)hs2, csr_row, offs, dinv, b2, out);
}

// Round 13
// 327.239 us; speedup vs baseline: 1.0879x; 1.0879x over previous
//
#include <hip/hip_runtime.h>

#define N_NODES 100000
#define N_EDGES 1600000
#define INC 128
#define HIDC 128
#define OUTC 64

// Binned scatter geometry: bucket = target >> 9 (512 targets/bucket)
constexpr int BSH = 9;
constexpr int BTGT = 1 << BSH;                                // 512
constexpr int NBUCK = (N_NODES + BTGT - 1) / BTGT;            // 196
constexpr int BCAP = 10240;                                   // fixed bucket capacity (mean 8163, sd~90)
constexpr int BIN_TILE = 2048;
constexpr int BIN_EPT = BIN_TILE / 256;                       // 8
constexpr int NBINBLK = (N_EDGES + BIN_TILE - 1) / BIN_TILE;  // 782

// ---------------- bf16 helpers ----------------

__device__ __forceinline__ float blo(unsigned u) { return __uint_as_float(u << 16); }
__device__ __forceinline__ float bhi(unsigned u) { return __uint_as_float(u & 0xFFFF0000u); }
__device__ __forceinline__ unsigned pack_bf2(float a, float b) {
    unsigned ua = __float_as_uint(a);
    ua = (ua + 0x7FFFu + ((ua >> 16) & 1u)) >> 16;
    unsigned ub = __float_as_uint(b);
    ub = (ub + 0x7FFFu + ((ub >> 16) & 1u)) >> 16;
    return ua | (ub << 16);
}

// ---------------- fixed-capacity binned CSR build (no pre-count) ----------------

__global__ void k_binit(int* __restrict__ bcur) {
    int b = threadIdx.x;
    if (b < NBUCK) bcur[b] = b * BCAP;
}

__global__ __launch_bounds__(256) void k_bin(const int* __restrict__ ei,
                                             int* __restrict__ bcur,
                                             unsigned* __restrict__ staging) {
    __shared__ int cnt[256];
    __shared__ int base[256];
    const int tid = threadIdx.x;
    cnt[tid] = 0;
    __syncthreads();
    const int e0 = blockIdx.x * BIN_TILE;
    unsigned pk[BIN_EPT];
    int bk[BIN_EPT];
#pragma unroll
    for (int r = 0; r < BIN_EPT; ++r) {
        int e = e0 + r * 256 + tid;
        if (e < N_EDGES) {
            int t = __builtin_nontemporal_load(ei + N_EDGES + e);
            int s = __builtin_nontemporal_load(ei + e);
            bk[r] = t >> BSH;
            pk[r] = ((unsigned)s << BSH) | (unsigned)(t & (BTGT - 1));
            atomicAdd(&cnt[bk[r]], 1);
        } else {
            bk[r] = -1;
        }
    }
    __syncthreads();
    if (tid < NBUCK) {
        int c = cnt[tid];
        base[tid] = (c > 0) ? atomicAdd(&bcur[tid], c) : 0;
    }
    __syncthreads();
#pragma unroll
    for (int r = 0; r < BIN_EPT; ++r) {
        if (bk[r] >= 0) {
            int g = atomicAdd(&base[bk[r]], 1);
            staging[g] = pk[r];
        }
    }
}

__global__ void k_bucket_scan(const int* __restrict__ bcur, int* __restrict__ bbase,
                              int* __restrict__ offs) {
    __shared__ int sdata[256];
    const int tid = threadIdx.x;
    int v = (tid < NBUCK) ? (bcur[tid] - tid * BCAP) : 0;
    sdata[tid] = v;
    __syncthreads();
    for (int off = 1; off < 256; off <<= 1) {
        int t = (tid >= off) ? sdata[tid - off] : 0;
        __syncthreads();
        sdata[tid] += t;
        __syncthreads();
    }
    if (tid < NBUCK) bbase[tid] = sdata[tid] - v;
    if (tid == 0) offs[N_NODES] = N_EDGES;
}

__global__ __launch_bounds__(256) void k_scatter2(const unsigned* __restrict__ staging,
                                                  const int* __restrict__ bcur,
                                                  const int* __restrict__ bbase,
                                                  int* __restrict__ offs,
                                                  float* __restrict__ dinv,
                                                  int* __restrict__ csr_row) {
    __shared__ int cnt[BTGT];
    __shared__ int pos[BTGT];
    __shared__ int sdata[256];
    const int b = blockIdx.x;
    const int tid = threadIdx.x;
    const int segb = b * BCAP;
    const int n = bcur[b] - segb;
    const int g0 = b << BSH;
    const int bb = bbase[b];
    cnt[tid] = 0;
    cnt[tid + 256] = 0;
    __syncthreads();
    for (int j = tid; j < n; j += 256) {
        atomicAdd(&cnt[staging[segb + j] & (BTGT - 1)], 1);
    }
    __syncthreads();
    const int c0 = cnt[2 * tid], c1 = cnt[2 * tid + 1];
    const int s = c0 + c1;
    sdata[tid] = s;
    __syncthreads();
    for (int off = 1; off < 256; off <<= 1) {
        int t = (tid >= off) ? sdata[tid - off] : 0;
        __syncthreads();
        sdata[tid] += t;
        __syncthreads();
    }
    const int texcl = sdata[tid] - s;
    const int o0 = bb + texcl;
    const int o1 = o0 + c0;
    const int gg0 = g0 + 2 * tid, gg1 = g0 + 2 * tid + 1;
    if (gg0 < N_NODES) {
        offs[gg0] = o0;
        dinv[gg0] = (c0 > 0) ? rsqrtf((float)c0) : 0.f;
    }
    if (gg1 < N_NODES) {
        offs[gg1] = o1;
        dinv[gg1] = (c1 > 0) ? rsqrtf((float)c1) : 0.f;
    }
    pos[2 * tid] = o0;
    pos[2 * tid + 1] = o1;
    __syncthreads();
    for (int j = tid; j < n; j += 256) {
        unsigned p = staging[segb + j];
        int lt = p & (BTGT - 1);
        int src = (int)(p >> BSH);
        int pp = atomicAdd(&pos[lt], 1);
        csr_row[pp] = src;
    }
}

// ---------------- dinv-scaled GEMM -> bf16, fully conflict-free ----------------
// 4 CONSECUTIVE rows per thread + odd pad 33: xs broadcast reads hit distinct
// banks (spacing-4 rows x stride 132 dwords -> banks 4 apart). Scalar LDS
// staging writes (odd pad forbids float4 LDS stores). wa/wb de-interleaved.
// BF16IN: X rows are bf16 (h buffer) -> halved fetch.

template <int BN, int OUTTOT, bool BF16IN>
__global__ __launch_bounds__(256) void k_gemm4(const void* __restrict__ Xv,
                                               const float* __restrict__ W,
                                               const float* __restrict__ dinv,
                                               unsigned short* __restrict__ outb) {
    constexpr int OG = OUTTOT / 8;   // out groups: 16 (L1) / 8 (L2)
    constexpr int NG = 256 / OG;     // 16 / 32; NG*4 == BN
    static_assert(NG * 4 == BN, "tile mismatch");
    constexpr int KC = 32;
    constexpr int HW = OUTTOT / 2;
    constexpr int PAD = KC + 1;      // 33 (odd)

    __shared__ float xs[BN][PAD];
    __shared__ float wa[KC][HW];
    __shared__ float wb[KC][HW];

    const int tid = threadIdx.x;
    const int oq = tid % OG;
    const int nq = tid / OG;
    const int r0 = nq * 4;
    const int n0 = blockIdx.x * BN;
    float acc[4][8] = {};

    for (int kc = 0; kc < 128; kc += KC) {
        if (BF16IN) {
            constexpr int ITER = (BN * KC) / (256 * 8);  // L2: 2
            const unsigned short* X = (const unsigned short*)Xv;
#pragma unroll
            for (int m = 0; m < (ITER > 0 ? ITER : 1); ++m) {
                int q = tid + 256 * m;
                int row = q / (KC / 8);
                int kq = q % (KC / 8);
                int nn = n0 + row;
                uint4 v = make_uint4(0u, 0u, 0u, 0u);
                if (nn < N_NODES)
                    v = *reinterpret_cast<const uint4*>(X + (size_t)nn * 128 + kc + kq * 8);
                float* d = &xs[row][kq * 8];
                d[0] = blo(v.x); d[1] = bhi(v.x);
                d[2] = blo(v.y); d[3] = bhi(v.y);
                d[4] = blo(v.z); d[5] = bhi(v.z);
                d[6] = blo(v.w); d[7] = bhi(v.w);
            }
        } else {
            constexpr int ITER = (BN * KC) / (256 * 4);  // L1: 2
            const float* X = (const float*)Xv;
#pragma unroll
            for (int m = 0; m < (ITER > 0 ? ITER : 1); ++m) {
                int q = tid + 256 * m;
                int row = q / (KC / 4);
                int kq = q % (KC / 4);
                int nn = n0 + row;
                float4 v = make_float4(0.f, 0.f, 0.f, 0.f);
                if (nn < N_NODES)
                    v = *reinterpret_cast<const float4*>(X + (size_t)nn * 128 + kc + kq * 4);
                float* d = &xs[row][kq * 4];
                d[0] = v.x; d[1] = v.y; d[2] = v.z; d[3] = v.w;
            }
        }
        constexpr int WITER = (KC * OUTTOT) / 1024;  // 4 / 2
#pragma unroll
        for (int m = 0; m < WITER; ++m) {
            int q = tid + 256 * m;
            int row = q / (OUTTOT / 4);
            int fq = q % (OUTTOT / 4);
            float4 v = *reinterpret_cast<const float4*>(W + (size_t)(kc + row) * OUTTOT + fq * 4);
            float* dst = (fq & 1) ? &wb[row][(fq >> 1) * 4] : &wa[row][(fq >> 1) * 4];
            *reinterpret_cast<float4*>(dst) = v;
        }
        __syncthreads();
#pragma unroll 8
        for (int k = 0; k < KC; ++k) {
            const float4 w0 = *reinterpret_cast<const float4*>(&wa[k][oq * 4]);
            const float4 w1 = *reinterpret_cast<const float4*>(&wb[k][oq * 4]);
#pragma unroll
            for (int j = 0; j < 4; ++j) {
                float xv = xs[r0 + j][k];
                acc[j][0] += xv * w0.x;
                acc[j][1] += xv * w0.y;
                acc[j][2] += xv * w0.z;
                acc[j][3] += xv * w0.w;
                acc[j][4] += xv * w1.x;
                acc[j][5] += xv * w1.y;
                acc[j][6] += xv * w1.z;
                acc[j][7] += xv * w1.w;
            }
        }
        __syncthreads();
    }
#pragma unroll
    for (int j = 0; j < 4; ++j) {
        int nn = n0 + r0 + j;
        if (nn < N_NODES) {
            float s = dinv[nn];
            uint4 pkv;
            pkv.x = pack_bf2(acc[j][0] * s, acc[j][1] * s);
            pkv.y = pack_bf2(acc[j][2] * s, acc[j][3] * s);
            pkv.z = pack_bf2(acc[j][4] * s, acc[j][5] * s);
            pkv.w = pack_bf2(acc[j][6] * s, acc[j][7] * s);
            *reinterpret_cast<uint4*>(outb + (size_t)nn * OUTTOT + oq * 8) = pkv;
        }
    }
}

// ---------------- CSR aggregation (R8 k_aggv, floor config) ----------------
// One wave per node. LPR lanes x 16B uint4 cover the row; SLOTS edge slots;
// U gathers in flight per lane; nt index loads; shfl_xor cross-slot reduce.
// BF16OUT packs the result (halves write traffic for the h buffer).

template <int OC, int U, bool RELU, bool BF16OUT>
__global__ __launch_bounds__(256) void k_aggv(const uint4* __restrict__ hs,
                                              const int* __restrict__ csr_row,
                                              const int* __restrict__ offs,
                                              const float* __restrict__ dinv,
                                              const float* __restrict__ bias,
                                              void* __restrict__ outv) {
    constexpr int LPR = (OC * 2) / 16;   // 16 (OC=128) or 8 (OC=64)
    constexpr int SLOTS = 64 / LPR;      // 4 or 8
    const int lane = threadIdx.x & 63;
    const int sub = lane / LPR;
    const int q = lane % LPR;
    const int wid = (blockIdx.x * 4) + (threadIdx.x >> 6);
    const int nwaves = gridDim.x * 4;

    for (int t = wid; t < N_NODES; t += nwaves) {
        const int s = offs[t], e2 = offs[t + 1];
        float acc[8] = {0.f, 0.f, 0.f, 0.f, 0.f, 0.f, 0.f, 0.f};
        for (int j = s; j < e2; j += U * SLOTS) {
            int rr[U];
#pragma unroll
            for (int u = 0; u < U; ++u) {
                int jj = j + u * SLOTS + sub;
                rr[u] = (jj < e2) ? __builtin_nontemporal_load(csr_row + jj) : -1;
            }
            uint4 vv[U];
#pragma unroll
            for (int u = 0; u < U; ++u) {
                vv[u] = make_uint4(0u, 0u, 0u, 0u);
                if (rr[u] >= 0) vv[u] = hs[(size_t)rr[u] * LPR + q];
            }
#pragma unroll
            for (int u = 0; u < U; ++u) {
                acc[0] += blo(vv[u].x);
                acc[1] += bhi(vv[u].x);
                acc[2] += blo(vv[u].y);
                acc[3] += bhi(vv[u].y);
                acc[4] += blo(vv[u].z);
                acc[5] += bhi(vv[u].z);
                acc[6] += blo(vv[u].w);
                acc[7] += bhi(vv[u].w);
            }
        }
#pragma unroll
        for (int off = 32; off >= LPR; off >>= 1) {
#pragma unroll
            for (int i = 0; i < 8; ++i) acc[i] += __shfl_xor(acc[i], off);
        }
        if (lane < LPR) {
            const float dt = dinv[t];
            const float4 b0 = *reinterpret_cast<const float4*>(bias + lane * 8);
            const float4 b1 = *reinterpret_cast<const float4*>(bias + lane * 8 + 4);
            float4 r0, r1;
            r0.x = acc[0] * dt + b0.x;
            r0.y = acc[1] * dt + b0.y;
            r0.z = acc[2] * dt + b0.z;
            r0.w = acc[3] * dt + b0.w;
            r1.x = acc[4] * dt + b1.x;
            r1.y = acc[5] * dt + b1.y;
            r1.z = acc[6] * dt + b1.z;
            r1.w = acc[7] * dt + b1.w;
            if (RELU) {
                r0.x = fmaxf(r0.x, 0.f); r0.y = fmaxf(r0.y, 0.f);
                r0.z = fmaxf(r0.z, 0.f); r0.w = fmaxf(r0.w, 0.f);
                r1.x = fmaxf(r1.x, 0.f); r1.y = fmaxf(r1.y, 0.f);
                r1.z = fmaxf(r1.z, 0.f); r1.w = fmaxf(r1.w, 0.f);
            }
            if (BF16OUT) {
                unsigned short* o = (unsigned short*)outv + (size_t)t * OC + lane * 8;
                uint4 pk;
                pk.x = pack_bf2(r0.x, r0.y);
                pk.y = pack_bf2(r0.z, r0.w);
                pk.z = pack_bf2(r1.x, r1.y);
                pk.w = pack_bf2(r1.z, r1.w);
                *reinterpret_cast<uint4*>(o) = pk;
            } else {
                float* po = (float*)outv + (size_t)t * OC + lane * 8;
                *reinterpret_cast<float4*>(po) = r0;
                *reinterpret_cast<float4*>(po + 4) = r1;
            }
        }
    }
}

// ---------------- layer-2 aggregation (R10 k_aggp, 2-node pipelined) ----------------

template <int OC, int U, bool RELU>
__global__ __launch_bounds__(256) void k_aggp(const uint4* __restrict__ hs,
                                              const int* __restrict__ csr_row,
                                              const int* __restrict__ offs,
                                              const float* __restrict__ dinv,
                                              const float* __restrict__ bias,
                                              float* __restrict__ out) {
    constexpr int LPR = (OC * 2) / 16;   // 8 for OC=64
    constexpr int SLOTS = 64 / LPR;      // 8
    const int lane = threadIdx.x & 63;
    const int sub = lane / LPR;
    const int q = lane % LPR;
    const int wid = (blockIdx.x * 4) + (threadIdx.x >> 6);
    const int nwaves = gridDim.x * 4;

    for (int t0 = wid * 2; t0 < N_NODES; t0 += nwaves * 2) {
        const int t1 = t0 + 1;
        const int s0 = offs[t0], e0 = offs[t0 + 1];
        const int s1 = offs[t1], e1 = offs[t1 + 1];
        float a0[8] = {}, a1[8] = {};
        int j0 = s0, j1 = s1;
        while (j0 < e0 || j1 < e1) {
            int r0[U], r1[U];
#pragma unroll
            for (int u = 0; u < U; ++u) {
                int jj = j0 + u * SLOTS + sub;
                r0[u] = (jj < e0) ? __builtin_nontemporal_load(csr_row + jj) : -1;
            }
#pragma unroll
            for (int u = 0; u < U; ++u) {
                int jj = j1 + u * SLOTS + sub;
                r1[u] = (jj < e1) ? __builtin_nontemporal_load(csr_row + jj) : -1;
            }
            uint4 v0[U], v1[U];
#pragma unroll
            for (int u = 0; u < U; ++u) {
                v0[u] = make_uint4(0u, 0u, 0u, 0u);
                if (r0[u] >= 0) v0[u] = hs[(size_t)r0[u] * LPR + q];
            }
#pragma unroll
            for (int u = 0; u < U; ++u) {
                v1[u] = make_uint4(0u, 0u, 0u, 0u);
                if (r1[u] >= 0) v1[u] = hs[(size_t)r1[u] * LPR + q];
            }
#pragma unroll
            for (int u = 0; u < U; ++u) {
                a0[0] += blo(v0[u].x); a0[1] += bhi(v0[u].x);
                a0[2] += blo(v0[u].y); a0[3] += bhi(v0[u].y);
                a0[4] += blo(v0[u].z); a0[5] += bhi(v0[u].z);
                a0[6] += blo(v0[u].w); a0[7] += bhi(v0[u].w);
                a1[0] += blo(v1[u].x); a1[1] += bhi(v1[u].x);
                a1[2] += blo(v1[u].y); a1[3] += bhi(v1[u].y);
                a1[4] += blo(v1[u].z); a1[5] += bhi(v1[u].z);
                a1[6] += blo(v1[u].w); a1[7] += bhi(v1[u].w);
            }
            j0 += U * SLOTS;
            j1 += U * SLOTS;
        }
#pragma unroll
        for (int off = 32; off >= LPR; off >>= 1) {
#pragma unroll
            for (int i = 0; i < 8; ++i) {
                a0[i] += __shfl_xor(a0[i], off);
                a1[i] += __shfl_xor(a1[i], off);
            }
        }
        if (lane < LPR) {
            const float4 b0 = *reinterpret_cast<const float4*>(bias + lane * 8);
            const float4 b1 = *reinterpret_cast<const float4*>(bias + lane * 8 + 4);
            const float d0 = dinv[t0], d1 = dinv[t1];
            float4 r0, r1, r2, r3;
            r0.x = a0[0] * d0 + b0.x; r0.y = a0[1] * d0 + b0.y;
            r0.z = a0[2] * d0 + b0.z; r0.w = a0[3] * d0 + b0.w;
            r1.x = a0[4] * d0 + b1.x; r1.y = a0[5] * d0 + b1.y;
            r1.z = a0[6] * d0 + b1.z; r1.w = a0[7] * d0 + b1.w;
            r2.x = a1[0] * d1 + b0.x; r2.y = a1[1] * d1 + b0.y;
            r2.z = a1[2] * d1 + b0.z; r2.w = a1[3] * d1 + b0.w;
            r3.x = a1[4] * d1 + b1.x; r3.y = a1[5] * d1 + b1.y;
            r3.z = a1[6] * d1 + b1.z; r3.w = a1[7] * d1 + b1.w;
            if (RELU) {
                r0.x = fmaxf(r0.x, 0.f); r0.y = fmaxf(r0.y, 0.f);
                r0.z = fmaxf(r0.z, 0.f); r0.w = fmaxf(r0.w, 0.f);
                r1.x = fmaxf(r1.x, 0.f); r1.y = fmaxf(r1.y, 0.f);
                r1.z = fmaxf(r1.z, 0.f); r1.w = fmaxf(r1.w, 0.f);
                r2.x = fmaxf(r2.x, 0.f); r2.y = fmaxf(r2.y, 0.f);
                r2.z = fmaxf(r2.z, 0.f); r2.w = fmaxf(r2.w, 0.f);
                r3.x = fmaxf(r3.x, 0.f); r3.y = fmaxf(r3.y, 0.f);
                r3.z = fmaxf(r3.z, 0.f); r3.w = fmaxf(r3.w, 0.f);
            }
            float* p0 = out + (size_t)t0 * OC + lane * 8;
            float* p1 = out + (size_t)t1 * OC + lane * 8;
            *reinterpret_cast<float4*>(p0) = r0;
            *reinterpret_cast<float4*>(p0 + 4) = r1;
            *reinterpret_cast<float4*>(p1) = r2;
            *reinterpret_cast<float4*>(p1 + 4) = r3;
        }
    }
}

// ---------------- launch ----------------

extern "C" void kernel_launch(void* const* d_in, const int* in_sizes, int n_in,
                              void* d_out, int out_size, void* d_ws, size_t ws_size,
                              hipStream_t stream) {
    const float* x  = (const float*)d_in[0];
    const int*   ei = (const int*)d_in[1];
    const float* W1 = (const float*)d_in[2];
    const float* b1 = (const float*)d_in[3];
    const float* W2 = (const float*)d_in[4];
    const float* b2 = (const float*)d_in[5];
    float* out = (float*)d_out;

    char* w = (char*)d_ws;
    auto alloc = [&](size_t bytes) {
        void* p = (void*)w;
        w += (bytes + 255) & ~(size_t)255;
        return p;
    };
    float* dinv    = (float*)alloc((size_t)N_NODES * 4);
    int*   offs    = (int*)alloc((size_t)(N_NODES + 1) * 4);
    int*   bcur    = (int*)alloc((size_t)NBUCK * 4);
    int*   bbase   = (int*)alloc(256 * 4);
    unsigned* staging = (unsigned*)alloc((size_t)NBUCK * BCAP * 4); // 8.0 MB
    int*   csr_row = (int*)alloc((size_t)N_EDGES * 4);
    unsigned short* hs1 = (unsigned short*)alloc((size_t)N_NODES * HIDC * 2); // bf16
    unsigned short* h   = (unsigned short*)alloc((size_t)N_NODES * HIDC * 2); // bf16 now
    unsigned short* hs2 = hs1; // bf16, reuse (hs1 dead after layer-1 agg)

    // CSR + norm build (fixed-capacity buckets; no pre-count)
    k_binit<<<1, 256, 0, stream>>>(bcur);
    k_bin<<<NBINBLK, 256, 0, stream>>>(ei, bcur, staging);
    k_bucket_scan<<<1, 256, 0, stream>>>(bcur, bbase, offs);
    k_scatter2<<<NBUCK, 256, 0, stream>>>(staging, bcur, bbase, offs, dinv, csr_row);

    // layer 1: fp32 X, 64 nodes x 128 outs
    k_gemm4<64, HIDC, false><<<(N_NODES + 63) / 64, 256, 0, stream>>>(x, W1, dinv, hs1);
    k_aggv<HIDC, 4, true, true><<<2048, 256, 0, stream>>>((const uint4*)hs1, csr_row, offs,
                                                          dinv, b1, h);

    // layer 2: bf16 X (h), 128 nodes x 64 outs
    k_gemm4<128, OUTC, true><<<(N_NODES + 127) / 128, 256, 0, stream>>>(h, W2, dinv, hs2);
    k_aggp<OUTC, 2, false><<<2048, 256, 0, stream>>>((const uint4*)hs2, csr_row, offs,
                                                     dinv, b2, out);
}